// Round 7
// baseline (138.450 us; speedup 1.0000x reference)
//
#include <hip/hip_runtime.h>
#include <hip/hip_bf16.h>
#include <cstdint>

// Problem constants (B=2, S=2048, DIM=1024, H=16, KVH=4, HD=64, WINDOW=256)
#define S_LEN 2048
#define QKV_COLS 1536   // 1024 q | 256 k | 256 v

typedef __bf16 bf16_t;
typedef bf16_t bf16x8 __attribute__((ext_vector_type(8)));
typedef bf16_t bf16x4 __attribute__((ext_vector_type(4)));
typedef float f32x4 __attribute__((ext_vector_type(4)));

typedef __attribute__((address_space(1))) void as1_void;
typedef __attribute__((address_space(3))) void as3_void;

__device__ __forceinline__ void async_load16(const void* g, void* lds) {
  __builtin_amdgcn_global_load_lds(
      (as1_void*)(uintptr_t)g,
      (as3_void*)(uint32_t)(uintptr_t)lds,
      16, 0, 0);
}

__device__ __forceinline__ uint32_t pkbf(float a, float b) {
  union { bf16_t h[2]; uint32_t u; } c;
  c.h[0] = (bf16_t)a; c.h[1] = (bf16_t)b;
  return c.u;
}

// ---------------- f32 -> bf16 convert; Wo gets pair_mix premixed ------------
__global__ __launch_bounds__(256) void convert_all(
    const float4* __restrict__ x, const float4* __restrict__ wq,
    const float4* __restrict__ wk, const float4* __restrict__ wv,
    const float4* __restrict__ wo, const float* __restrict__ pm,
    bf16x4* __restrict__ xb, bf16x4* __restrict__ wqkvb, bf16x4* __restrict__ wob) {
  int u = blockIdx.x * 256 + threadIdx.x;
  if (u >= 1441792) {                       // Wo premix region
    int off = u - 1441792;                  // float4 index into 1024x1024
    int flat = off * 4;
    int row = flat >> 10, colf = flat & 1023;
    int col2p = colf & ~64;
    int p = colf >> 7, ii = (colf >> 6) & 1;
    float4 a = wo[(row * 1024 + col2p) >> 2];
    float4 bq = wo[(row * 1024 + (col2p | 64)) >> 2];
    float m0v = pm[p * 4 + ii], m1v = pm[p * 4 + 2 + ii];
    bf16x4 o4;
    o4[0] = (bf16_t)(m0v * a.x + m1v * bq.x);
    o4[1] = (bf16_t)(m0v * a.y + m1v * bq.y);
    o4[2] = (bf16_t)(m0v * a.z + m1v * bq.z);
    o4[3] = (bf16_t)(m0v * a.w + m1v * bq.w);
    wob[off] = o4;
    return;
  }
  const float4* src; bf16x4* dst; int off;
  if (u < 1048576)      { src = x;  dst = xb;             off = u; }
  else if (u < 1310720) { src = wq; dst = wqkvb;          off = u - 1048576; }
  else if (u < 1376256) { src = wk; dst = wqkvb + 262144; off = u - 1310720; }
  else                  { src = wv; dst = wqkvb + 327680; off = u - 1376256; }
  float4 f = src[off];
  bf16x4 o;
  o[0] = (bf16_t)f.x; o[1] = (bf16_t)f.y; o[2] = (bf16_t)f.z; o[3] = (bf16_t)f.w;
  dst[off] = o;
}

// ---------------- QKV GEMM: 64x128 tile, BK=64, dbuf + counted vmcnt --------
// R6-verified: 768 blocks = 3.0/CU balanced, double-buffered LDS, next tile's
// 6 global_load_lds stay in flight across the barrier via vmcnt(6).
// XCD swizzle: 768 = 8 x 96 bijective.
__global__ __launch_bounds__(256) void gemm_qkv(
    const bf16_t* __restrict__ A, const bf16_t* __restrict__ B,
    bf16_t* __restrict__ C, bf16_t* __restrict__ vt,
    const float* __restrict__ q_gain, int N, int K) {
  __shared__ bf16_t As[2][64 * 64];    // 2 x 8 KB
  __shared__ bf16_t Bs[2][128 * 64];   // 2 x 16 KB
  const int tid = threadIdx.x;
  const int lane = tid & 63;
  const int w = tid >> 6;
  const int wm = (w & 1) << 5, wn = (w >> 1) << 6;
  const int orig = blockIdx.y * gridDim.x + blockIdx.x;   // 0..767
  const int id = (orig & 7) * 96 + (orig >> 3);           // bijective (768%8==0)
  const int m0 = (id / 12) << 6, n0 = (id % 12) << 7;
  const int fidx = lane & 15, quad = lane >> 4;
  f32x4 acc[2][4] = {};
  int ra0 = (tid + 0) >> 3,   sa0 = ((tid + 0) & 7) ^ (ra0 & 7);
  int ra1 = (tid + 256) >> 3, sa1 = ((tid + 256) & 7) ^ (ra1 & 7);
  const bf16_t* Ag0 = A + (size_t)(m0 + ra0) * K + sa0 * 8;
  const bf16_t* Ag1 = A + (size_t)(m0 + ra1) * K + sa1 * 8;
  const bf16_t* Bg[4];
#pragma unroll
  for (int j = 0; j < 4; j++) {
    int c = tid + j * 256, r = c >> 3, s = (c & 7) ^ (r & 7);
    Bg[j] = B + (size_t)(n0 + r) * K + s * 8;
  }
  int aoff[2][2], boff[4][2];
#pragma unroll
  for (int mi = 0; mi < 2; mi++) {
    int row = wm + mi * 16 + fidx;
#pragma unroll
    for (int half = 0; half < 2; half++)
      aoff[mi][half] = row * 64 + (((half * 4 + quad) ^ (row & 7)) * 8);
  }
#pragma unroll
  for (int ni = 0; ni < 4; ni++) {
    int row = wn + ni * 16 + fidx;
#pragma unroll
    for (int half = 0; half < 2; half++)
      boff[ni][half] = row * 64 + (((half * 4 + quad) ^ (row & 7)) * 8);
  }
  // prologue: stage tile 0 into buffer 0 (6 loads/thread outstanding)
  async_load16(Ag0, &As[0][tid * 8]);
  async_load16(Ag1, &As[0][(tid + 256) * 8]);
#pragma unroll
  for (int j = 0; j < 4; j++)
    async_load16(Bg[j], &Bs[0][(tid + j * 256) * 8]);
  int cur = 0;
  for (int kt = 0; kt < K; kt += 64) {
    const int nk = kt + 64;
    if (nk < K) {
      async_load16(Ag0 + nk, &As[cur ^ 1][tid * 8]);
      async_load16(Ag1 + nk, &As[cur ^ 1][(tid + 256) * 8]);
#pragma unroll
      for (int j = 0; j < 4; j++)
        async_load16(Bg[j] + nk, &Bs[cur ^ 1][(tid + j * 256) * 8]);
      asm volatile("s_waitcnt vmcnt(6)" ::: "memory");  // cur landed; next 6 fly
    } else {
      asm volatile("s_waitcnt vmcnt(0)" ::: "memory");
    }
    __builtin_amdgcn_s_barrier();
    __builtin_amdgcn_sched_barrier(0);
    bf16x8 af[2][2], bfr[4][2];
#pragma unroll
    for (int mi = 0; mi < 2; mi++)
#pragma unroll
      for (int half = 0; half < 2; half++)
        af[mi][half] = *(const bf16x8*)(&As[cur][aoff[mi][half]]);
#pragma unroll
    for (int ni = 0; ni < 4; ni++)
#pragma unroll
      for (int half = 0; half < 2; half++)
        bfr[ni][half] = *(const bf16x8*)(&Bs[cur][boff[ni][half]]);
#pragma unroll
    for (int half = 0; half < 2; half++)
#pragma unroll
      for (int mi = 0; mi < 2; mi++)
#pragma unroll
        for (int ni = 0; ni < 4; ni++)
          acc[mi][ni] = __builtin_amdgcn_mfma_f32_16x16x32_bf16(
              af[mi][half], bfr[ni][half], acc[mi][ni], 0, 0, 0);
    asm volatile("s_waitcnt lgkmcnt(0)" ::: "memory");  // reads of cur done
    __builtin_amdgcn_s_barrier();                        // before cur restage
    cur ^= 1;
  }
  const int hc0 = n0 + wn;
  if (hc0 >= 1280) {
    // ---- V: transposed store into vt[(b*4+g)*64+dh][s]
#pragma unroll
    for (int mi = 0; mi < 2; mi++)
#pragma unroll
      for (int ni = 0; ni < 4; ni++) {
        int cg = (hc0 - 1280) + ni * 16 + fidx;
        int g = cg >> 6, dh = cg & 63;
        int srow = m0 + wm + mi * 16 + quad * 4;
        int bb = srow >> 11, si = srow & (S_LEN - 1);
        bf16x4 pack;
#pragma unroll
        for (int r = 0; r < 4; r++) pack[r] = (bf16_t)acc[mi][ni][r];
        *(bf16x4*)(vt + ((size_t)((bb * 4 + g) * 64 + dh)) * S_LEN + si) = pack;
      }
    return;
  }
  // ---- q/k: RMSNorm + RoPE (+gain for q)
  float gain = 1.f;
  if (hc0 < 1024) gain = q_gain[hc0 >> 6] * 0.125f;  // fold softmax scale
#pragma unroll
  for (int mi = 0; mi < 2; mi++)
#pragma unroll
    for (int r = 0; r < 4; r++) {
      float ss = 0.f;
#pragma unroll
      for (int ni = 0; ni < 4; ni++) { float t = acc[mi][ni][r]; ss += t * t; }
#pragma unroll
      for (int off = 8; off >= 1; off >>= 1) ss += __shfl_xor(ss, off);
      float scl = rsqrtf(ss * (1.f / 64.f) + 1e-6f);
      int s = (m0 + wm + mi * 16 + quad * 4 + r) & (S_LEN - 1);
#pragma unroll
      for (int ni = 0; ni < 2; ni++) {
        float v1 = acc[mi][ni][r] * scl;
        float v2 = acc[mi][ni + 2][r] * scl;
        float fr = (float)(ni * 16 + fidx);
        float ang = (float)s * __expf(fr * -0.28782313662425575f);  // ln(1e4)/32
        float sn, cs;
        __sincosf(ang, &sn, &cs);
        acc[mi][ni][r]     = (v1 * cs + v2 * sn) * gain;
        acc[mi][ni + 2][r] = (-v1 * sn + v2 * cs) * gain;
      }
    }
#pragma unroll
  for (int mi = 0; mi < 2; mi++)
#pragma unroll
    for (int ni = 0; ni < 4; ni++)
#pragma unroll
      for (int r = 0; r < 4; r++) {
        int gr = m0 + wm + mi * 16 + quad * 4 + r;
        int gc = n0 + wn + ni * 16 + fidx;
        C[(size_t)gr * N + gc] = (bf16_t)acc[mi][ni][r];
      }
}

// ---------------- out-proj GEMM: 64x128 tile, BK=64, dbuf + counted vmcnt ---
// R6-verified; 512 blocks = 2.0/CU balanced. XCD swizzle: 512 = 8 x 64.
__global__ __launch_bounds__(256) void gemm_bt_f32(
    const bf16_t* __restrict__ A, const bf16_t* __restrict__ B,
    float* __restrict__ C, int N, int K) {
  __shared__ bf16_t As[2][64 * 64];
  __shared__ bf16_t Bs[2][128 * 64];
  const int tid = threadIdx.x;
  const int lane = tid & 63;
  const int w = tid >> 6;
  const int wm = (w & 1) << 5, wn = (w >> 1) << 6;
  const int orig = blockIdx.y * gridDim.x + blockIdx.x;   // 0..511
  const int id = (orig & 7) * 64 + (orig >> 3);           // bijective (512%8==0)
  const int m0 = (id >> 3) << 6, n0 = (id & 7) << 7;
  const int fidx = lane & 15, quad = lane >> 4;
  f32x4 acc[2][4] = {};
  int ra0 = (tid + 0) >> 3,   sa0 = ((tid + 0) & 7) ^ (ra0 & 7);
  int ra1 = (tid + 256) >> 3, sa1 = ((tid + 256) & 7) ^ (ra1 & 7);
  const bf16_t* Ag0 = A + (size_t)(m0 + ra0) * K + sa0 * 8;
  const bf16_t* Ag1 = A + (size_t)(m0 + ra1) * K + sa1 * 8;
  const bf16_t* Bg[4];
#pragma unroll
  for (int j = 0; j < 4; j++) {
    int c = tid + j * 256, r = c >> 3, s = (c & 7) ^ (r & 7);
    Bg[j] = B + (size_t)(n0 + r) * K + s * 8;
  }
  int aoff[2][2], boff[4][2];
#pragma unroll
  for (int mi = 0; mi < 2; mi++) {
    int row = wm + mi * 16 + fidx;
#pragma unroll
    for (int half = 0; half < 2; half++)
      aoff[mi][half] = row * 64 + (((half * 4 + quad) ^ (row & 7)) * 8);
  }
#pragma unroll
  for (int ni = 0; ni < 4; ni++) {
    int row = wn + ni * 16 + fidx;
#pragma unroll
    for (int half = 0; half < 2; half++)
      boff[ni][half] = row * 64 + (((half * 4 + quad) ^ (row & 7)) * 8);
  }
  async_load16(Ag0, &As[0][tid * 8]);
  async_load16(Ag1, &As[0][(tid + 256) * 8]);
#pragma unroll
  for (int j = 0; j < 4; j++)
    async_load16(Bg[j], &Bs[0][(tid + j * 256) * 8]);
  int cur = 0;
  for (int kt = 0; kt < K; kt += 64) {
    const int nk = kt + 64;
    if (nk < K) {
      async_load16(Ag0 + nk, &As[cur ^ 1][tid * 8]);
      async_load16(Ag1 + nk, &As[cur ^ 1][(tid + 256) * 8]);
#pragma unroll
      for (int j = 0; j < 4; j++)
        async_load16(Bg[j] + nk, &Bs[cur ^ 1][(tid + j * 256) * 8]);
      asm volatile("s_waitcnt vmcnt(6)" ::: "memory");
    } else {
      asm volatile("s_waitcnt vmcnt(0)" ::: "memory");
    }
    __builtin_amdgcn_s_barrier();
    __builtin_amdgcn_sched_barrier(0);
    bf16x8 af[2][2], bfr[4][2];
#pragma unroll
    for (int mi = 0; mi < 2; mi++)
#pragma unroll
      for (int half = 0; half < 2; half++)
        af[mi][half] = *(const bf16x8*)(&As[cur][aoff[mi][half]]);
#pragma unroll
    for (int ni = 0; ni < 4; ni++)
#pragma unroll
      for (int half = 0; half < 2; half++)
        bfr[ni][half] = *(const bf16x8*)(&Bs[cur][boff[ni][half]]);
#pragma unroll
    for (int half = 0; half < 2; half++)
#pragma unroll
      for (int mi = 0; mi < 2; mi++)
#pragma unroll
        for (int ni = 0; ni < 4; ni++)
          acc[mi][ni] = __builtin_amdgcn_mfma_f32_16x16x32_bf16(
              af[mi][half], bfr[ni][half], acc[mi][ni], 0, 0, 0);
    asm volatile("s_waitcnt lgkmcnt(0)" ::: "memory");
    __builtin_amdgcn_s_barrier();
    cur ^= 1;
  }
#pragma unroll
  for (int mi = 0; mi < 2; mi++)
#pragma unroll
    for (int ni = 0; ni < 4; ni++)
#pragma unroll
      for (int r = 0; r < 4; r++) {
        int gr = m0 + wm + mi * 16 + quad * 4 + r;
        int gc = n0 + wn + ni * 16 + fidx;
        C[(size_t)gr * N + gc] = acc[mi][ni][r];
      }
}

// ---------------- MFMA flash attention, FIXED-SHIFT softmax -----------------
// R4-verified body + R7: K/V register double-buffer (T14 issue-early) — tile
// c+1's 8 global loads are issued before computing tile c, hiding ~200cy L2
// latency under the MFMA/exp/shfl chain (only 2 waves/SIMD resident, so TLP
// alone can't hide it). +32 VGPR, occupancy unaffected (grid-limited).
// XCD swizzle: 512 blocks = 8 XCDs x 64 -> each XCD owns one (b,g) slab.
#define FIXMAX 8.0f
#define OST 72  // O stage row stride: 144 B = 9*16 B, aligned
__global__ __launch_bounds__(256) void attn_mfma(
    const bf16_t* __restrict__ qkv, const bf16_t* __restrict__ vt,
    bf16_t* __restrict__ yb) {
  __shared__ bf16_t ob[4][32 * OST];
  const int tid = threadIdx.x, lane = tid & 63, w = tid >> 6;
  const int col = lane & 15, quad = lane >> 4;
  const int orig = blockIdx.z * 256 + blockIdx.y * 64 + blockIdx.x;  // 0..511
  const int id = (orig & 7) * 64 + (orig >> 3);                      // bijective
  const int q0 = (id & 63) * 32, g = (id >> 6) & 3, b = id >> 8;
  const int h = g * 4 + w;

  bf16x8 qf[2][2];
#pragma unroll
  for (int t = 0; t < 2; t++) {
    const bf16_t* qb =
        qkv + ((size_t)b * S_LEN + q0 + t * 16 + col) * QKV_COLS + h * 64 + quad * 8;
    qf[t][0] = *(const bf16x8*)qb;
    qf[t][1] = *(const bf16x8*)(qb + 32);
  }
  const bf16_t* kbase = qkv + (size_t)b * S_LEN * QKV_COLS + 1024 + g * 64 + quad * 8;
  const bf16_t* vbase = vt + ((size_t)((b * 4 + g) * 64) + col) * S_LEN + quad * 8;

  f32x4 o[2][4] = {};
  float ps[2] = {};   // per-lane partial row sum for q = col (reduced at end)

  const int c_lo = max(0, (q0 - 255) >> 5);
  const int c_hi = (q0 + 31) >> 5;

  bf16x8 kf[2][2], vf[4];
  {
    const int k0 = c_lo * 32;
#pragma unroll
    for (int nt = 0; nt < 2; nt++) {
      const bf16_t* kp = kbase + (size_t)(k0 + nt * 16 + col) * QKV_COLS;
      kf[nt][0] = *(const bf16x8*)kp;
      kf[nt][1] = *(const bf16x8*)(kp + 32);
    }
#pragma unroll
    for (int nt2 = 0; nt2 < 4; nt2++)
      vf[nt2] = *(const bf16x8*)(vbase + (size_t)(nt2 * 16) * S_LEN + k0);
  }

  for (int c = c_lo; c <= c_hi; c++) {
    const int k0 = c * 32;
    // ---- issue next tile's loads BEFORE computing this tile (T14)
    bf16x8 nkf[2][2], nvf[4];
    const bool has_next = (c < c_hi);
    if (has_next) {
      const int k1 = k0 + 32;
#pragma unroll
      for (int nt = 0; nt < 2; nt++) {
        const bf16_t* kp = kbase + (size_t)(k1 + nt * 16 + col) * QKV_COLS;
        nkf[nt][0] = *(const bf16x8*)kp;
        nkf[nt][1] = *(const bf16x8*)(kp + 32);
      }
#pragma unroll
      for (int nt2 = 0; nt2 < 4; nt2++)
        nvf[nt2] = *(const bf16x8*)(vbase + (size_t)(nt2 * 16) * S_LEN + k1);
    }

#pragma unroll
    for (int t = 0; t < 2; t++) {
      const int qt0 = q0 + t * 16;
      if (k0 > qt0 + 15) continue;          // fully above diagonal for this tile
      // S^T[k][q]: rows k = k0 + nt*16 + quad*4 + r, cols q = qt0 + col
      f32x4 st[2];
#pragma unroll
      for (int nt = 0; nt < 2; nt++) {
        f32x4 a = {};
        a = __builtin_amdgcn_mfma_f32_16x16x32_bf16(kf[nt][0], qf[t][0], a, 0, 0, 0);
        a = __builtin_amdgcn_mfma_f32_16x16x32_bf16(kf[nt][1], qf[t][1], a, 0, 0, 0);
        st[nt] = a;
      }
      const bool needmask = (k0 + 31 > qt0) || (k0 < qt0 - 224);  // wave-uniform
      float p2[2][4];
      if (needmask) {
        int q = qt0 + col;
#pragma unroll
        for (int nt = 0; nt < 2; nt++)
#pragma unroll
          for (int r = 0; r < 4; r++) {
            int k = k0 + nt * 16 + quad * 4 + r;
            bool valid = (k <= q) && (q - k < 256);
            p2[nt][r] = valid ? __expf(st[nt][r] - FIXMAX) : 0.f;
          }
      } else {
#pragma unroll
        for (int nt = 0; nt < 2; nt++)
#pragma unroll
          for (int r = 0; r < 4; r++)
            p2[nt][r] = __expf(st[nt][r] - FIXMAX);
      }
#pragma unroll
      for (int nt = 0; nt < 2; nt++)
#pragma unroll
        for (int r = 0; r < 4; r++) ps[t] += p2[nt][r];
      // pack pairs (r even = low half) and redistribute to A-fragment layout:
      // target (col,quad) dword m holds P[q=col][k = quad*8 + 2m, 2m+1]
      uint32_t pk0[2], pk1[2];
      pk0[0] = pkbf(p2[0][0], p2[0][1]); pk0[1] = pkbf(p2[0][2], p2[0][3]);
      pk1[0] = pkbf(p2[1][0], p2[1][1]); pk1[1] = pkbf(p2[1][2], p2[1][3]);
      uint32_t w32[4];
#pragma unroll
      for (int m = 0; m < 4; m++) {
        int srclane = col + 16 * ((2 * quad + (m >> 1)) & 3);
        uint32_t a0 = (uint32_t)__shfl((int)pk0[m & 1], srclane);
        uint32_t a1 = (uint32_t)__shfl((int)pk1[m & 1], srclane);
        w32[m] = (quad < 2) ? a0 : a1;
      }
      union { uint32_t u[4]; bf16x8 v; } pu;
      pu.u[0] = w32[0]; pu.u[1] = w32[1]; pu.u[2] = w32[2]; pu.u[3] = w32[3];
      bf16x8 pf = pu.v;
#pragma unroll
      for (int nt2 = 0; nt2 < 4; nt2++)
        o[t][nt2] = __builtin_amdgcn_mfma_f32_16x16x32_bf16(pf, vf[nt2], o[t][nt2], 0, 0, 0);
    }
    if (has_next) {
#pragma unroll
      for (int nt = 0; nt < 2; nt++) { kf[nt][0] = nkf[nt][0]; kf[nt][1] = nkf[nt][1]; }
#pragma unroll
      for (int nt2 = 0; nt2 < 4; nt2++) vf[nt2] = nvf[nt2];
    }
  }
  // ---- row-sum reduce (across quads), fetch per-output-row inverse, store
#pragma unroll
  for (int t = 0; t < 2; t++) {
    float v = ps[t];
    v += __shfl_xor(v, 16);
    v += __shfl_xor(v, 32);
    float il = 1.f / v;               // inverse row sum for q = col
    float il4[4];
#pragma unroll
    for (int r = 0; r < 4; r++) il4[r] = __shfl(il, quad * 4 + r);
    int row0 = t * 16 + quad * 4;
#pragma unroll
    for (int nt2 = 0; nt2 < 4; nt2++)
#pragma unroll
      for (int r = 0; r < 4; r++)
        ob[w][(row0 + r) * OST + nt2 * 16 + col] = (bf16_t)(o[t][nt2][r] * il4[r]);
  }
  asm volatile("s_waitcnt lgkmcnt(0)" ::: "memory");
#pragma unroll
  for (int it = 0; it < 4; it++) {
    int row = it * 8 + (lane >> 3);       // 0..31
    int d0 = (lane & 7) * 8;
    bf16x8 v8 = *(const bf16x8*)(ob[w] + row * OST + d0);
    *(bf16x8*)(yb + ((size_t)b * S_LEN + q0 + row) * 1024 + h * 64 + d0) = v8;
  }
}

extern "C" void kernel_launch(void* const* d_in, const int* in_sizes, int n_in,
                              void* d_out, int out_size, void* d_ws, size_t ws_size,
                              hipStream_t stream) {
  const float* x        = (const float*)d_in[0];
  const float* Wq       = (const float*)d_in[1];
  const float* Wk       = (const float*)d_in[2];
  const float* Wv       = (const float*)d_in[3];
  const float* Wo       = (const float*)d_in[4];
  const float* q_gain   = (const float*)d_in[5];
  const float* pair_mix = (const float*)d_in[6];
  float* out = (float*)d_out;

  bf16_t* ws    = (bf16_t*)d_ws;
  bf16_t* xb    = ws;                   // 4096*1024
  bf16_t* wqkvb = xb + 4096 * 1024;     // 1536*1024
  bf16_t* wob   = wqkvb + 1536 * 1024;  // 1024*1024 (premixed)
  bf16_t* qkvb  = wob + 1024 * 1024;    // 4096*1536
  bf16_t* yb    = qkvb + 4096 * 1536;   // 4096*1024
  bf16_t* vt    = yb + 4096 * 1024;     // 8*64*2048 (total ~36.7 MB)

  convert_all<<<6656, 256, 0, stream>>>(
      (const float4*)x, (const float4*)Wq, (const float4*)Wk, (const float4*)Wv,
      (const float4*)Wo, pair_mix, (bf16x4*)xb, (bf16x4*)wqkvb, (bf16x4*)wob);
  gemm_qkv<<<dim3(12, 64), 256, 0, stream>>>(xb, wqkvb, qkvb, vt, q_gain, 1536, 1024);
  attn_mfma<<<dim3(64, 4, 2), 256, 0, stream>>>(qkvb, vt, yb);
  gemm_bt_f32<<<dim3(8, 64), 256, 0, stream>>>(yb, wob, out, 1024, 1024);
}

// Round 9
// 137.405 us; speedup vs baseline: 1.0076x; 1.0076x over previous
//
#include <hip/hip_runtime.h>
#include <hip/hip_bf16.h>
#include <cstdint>

// Problem constants (B=2, S=2048, DIM=1024, H=16, KVH=4, HD=64, WINDOW=256)
#define S_LEN 2048
#define QKV_COLS 1536   // 1024 q | 256 k | 256 v

typedef __bf16 bf16_t;
typedef bf16_t bf16x8 __attribute__((ext_vector_type(8)));
typedef bf16_t bf16x4 __attribute__((ext_vector_type(4)));
typedef float f32x4 __attribute__((ext_vector_type(4)));

typedef __attribute__((address_space(1))) void as1_void;
typedef __attribute__((address_space(3))) void as3_void;

__device__ __forceinline__ void async_load16(const void* g, void* lds) {
  __builtin_amdgcn_global_load_lds(
      (as1_void*)(uintptr_t)g,
      (as3_void*)(uint32_t)(uintptr_t)lds,
      16, 0, 0);
}

__device__ __forceinline__ uint32_t pkbf(float a, float b) {
  union { bf16_t h[2]; uint32_t u; } c;
  c.h[0] = (bf16_t)a; c.h[1] = (bf16_t)b;
  return c.u;
}

// ---------------- f32 -> bf16 convert; Wo gets pair_mix premixed ------------
__global__ __launch_bounds__(256) void convert_all(
    const float4* __restrict__ x, const float4* __restrict__ wq,
    const float4* __restrict__ wk, const float4* __restrict__ wv,
    const float4* __restrict__ wo, const float* __restrict__ pm,
    bf16x4* __restrict__ xb, bf16x4* __restrict__ wqkvb, bf16x4* __restrict__ wob) {
  int u = blockIdx.x * 256 + threadIdx.x;
  if (u >= 1441792) {                       // Wo premix region
    int off = u - 1441792;                  // float4 index into 1024x1024
    int flat = off * 4;
    int row = flat >> 10, colf = flat & 1023;
    int col2p = colf & ~64;
    int p = colf >> 7, ii = (colf >> 6) & 1;
    float4 a = wo[(row * 1024 + col2p) >> 2];
    float4 bq = wo[(row * 1024 + (col2p | 64)) >> 2];
    float m0v = pm[p * 4 + ii], m1v = pm[p * 4 + 2 + ii];
    bf16x4 o4;
    o4[0] = (bf16_t)(m0v * a.x + m1v * bq.x);
    o4[1] = (bf16_t)(m0v * a.y + m1v * bq.y);
    o4[2] = (bf16_t)(m0v * a.z + m1v * bq.z);
    o4[3] = (bf16_t)(m0v * a.w + m1v * bq.w);
    wob[off] = o4;
    return;
  }
  const float4* src; bf16x4* dst; int off;
  if (u < 1048576)      { src = x;  dst = xb;             off = u; }
  else if (u < 1310720) { src = wq; dst = wqkvb;          off = u - 1048576; }
  else if (u < 1376256) { src = wk; dst = wqkvb + 262144; off = u - 1310720; }
  else                  { src = wv; dst = wqkvb + 327680; off = u - 1376256; }
  float4 f = src[off];
  bf16x4 o;
  o[0] = (bf16_t)f.x; o[1] = (bf16_t)f.y; o[2] = (bf16_t)f.z; o[3] = (bf16_t)f.w;
  dst[off] = o;
}

// ---------------- QKV GEMM: 64x128 tile, BK=64, dbuf + counted vmcnt --------
// R6-verified: 768 blocks = 3.0/CU balanced, double-buffered LDS, next tile's
// 6 global_load_lds stay in flight across the barrier via vmcnt(6).
// XCD swizzle: 768 = 8 x 96 bijective.
__global__ __launch_bounds__(256) void gemm_qkv(
    const bf16_t* __restrict__ A, const bf16_t* __restrict__ B,
    bf16_t* __restrict__ C, bf16_t* __restrict__ vt,
    const float* __restrict__ q_gain, int N, int K) {
  __shared__ bf16_t As[2][64 * 64];    // 2 x 8 KB
  __shared__ bf16_t Bs[2][128 * 64];   // 2 x 16 KB
  const int tid = threadIdx.x;
  const int lane = tid & 63;
  const int w = tid >> 6;
  const int wm = (w & 1) << 5, wn = (w >> 1) << 6;
  const int orig = blockIdx.y * gridDim.x + blockIdx.x;   // 0..767
  const int id = (orig & 7) * 96 + (orig >> 3);           // bijective (768%8==0)
  const int m0 = (id / 12) << 6, n0 = (id % 12) << 7;
  const int fidx = lane & 15, quad = lane >> 4;
  f32x4 acc[2][4] = {};
  int ra0 = (tid + 0) >> 3,   sa0 = ((tid + 0) & 7) ^ (ra0 & 7);
  int ra1 = (tid + 256) >> 3, sa1 = ((tid + 256) & 7) ^ (ra1 & 7);
  const bf16_t* Ag0 = A + (size_t)(m0 + ra0) * K + sa0 * 8;
  const bf16_t* Ag1 = A + (size_t)(m0 + ra1) * K + sa1 * 8;
  const bf16_t* Bg[4];
#pragma unroll
  for (int j = 0; j < 4; j++) {
    int c = tid + j * 256, r = c >> 3, s = (c & 7) ^ (r & 7);
    Bg[j] = B + (size_t)(n0 + r) * K + s * 8;
  }
  int aoff[2][2], boff[4][2];
#pragma unroll
  for (int mi = 0; mi < 2; mi++) {
    int row = wm + mi * 16 + fidx;
#pragma unroll
    for (int half = 0; half < 2; half++)
      aoff[mi][half] = row * 64 + (((half * 4 + quad) ^ (row & 7)) * 8);
  }
#pragma unroll
  for (int ni = 0; ni < 4; ni++) {
    int row = wn + ni * 16 + fidx;
#pragma unroll
    for (int half = 0; half < 2; half++)
      boff[ni][half] = row * 64 + (((half * 4 + quad) ^ (row & 7)) * 8);
  }
  // prologue: stage tile 0 into buffer 0 (6 loads/thread outstanding)
  async_load16(Ag0, &As[0][tid * 8]);
  async_load16(Ag1, &As[0][(tid + 256) * 8]);
#pragma unroll
  for (int j = 0; j < 4; j++)
    async_load16(Bg[j], &Bs[0][(tid + j * 256) * 8]);
  int cur = 0;
  for (int kt = 0; kt < K; kt += 64) {
    const int nk = kt + 64;
    if (nk < K) {
      async_load16(Ag0 + nk, &As[cur ^ 1][tid * 8]);
      async_load16(Ag1 + nk, &As[cur ^ 1][(tid + 256) * 8]);
#pragma unroll
      for (int j = 0; j < 4; j++)
        async_load16(Bg[j] + nk, &Bs[cur ^ 1][(tid + j * 256) * 8]);
      asm volatile("s_waitcnt vmcnt(6)" ::: "memory");  // cur landed; next 6 fly
    } else {
      asm volatile("s_waitcnt vmcnt(0)" ::: "memory");
    }
    __builtin_amdgcn_s_barrier();
    __builtin_amdgcn_sched_barrier(0);
    bf16x8 af[2][2], bfr[4][2];
#pragma unroll
    for (int mi = 0; mi < 2; mi++)
#pragma unroll
      for (int half = 0; half < 2; half++)
        af[mi][half] = *(const bf16x8*)(&As[cur][aoff[mi][half]]);
#pragma unroll
    for (int ni = 0; ni < 4; ni++)
#pragma unroll
      for (int half = 0; half < 2; half++)
        bfr[ni][half] = *(const bf16x8*)(&Bs[cur][boff[ni][half]]);
#pragma unroll
    for (int half = 0; half < 2; half++)
#pragma unroll
      for (int mi = 0; mi < 2; mi++)
#pragma unroll
        for (int ni = 0; ni < 4; ni++)
          acc[mi][ni] = __builtin_amdgcn_mfma_f32_16x16x32_bf16(
              af[mi][half], bfr[ni][half], acc[mi][ni], 0, 0, 0);
    asm volatile("s_waitcnt lgkmcnt(0)" ::: "memory");  // reads of cur done
    __builtin_amdgcn_s_barrier();                        // before cur restage
    cur ^= 1;
  }
  const int hc0 = n0 + wn;
  if (hc0 >= 1280) {
    // ---- V: transposed store into vt[(b*4+g)*64+dh][s]
#pragma unroll
    for (int mi = 0; mi < 2; mi++)
#pragma unroll
      for (int ni = 0; ni < 4; ni++) {
        int cg = (hc0 - 1280) + ni * 16 + fidx;
        int g = cg >> 6, dh = cg & 63;
        int srow = m0 + wm + mi * 16 + quad * 4;
        int bb = srow >> 11, si = srow & (S_LEN - 1);
        bf16x4 pack;
#pragma unroll
        for (int r = 0; r < 4; r++) pack[r] = (bf16_t)acc[mi][ni][r];
        *(bf16x4*)(vt + ((size_t)((bb * 4 + g) * 64 + dh)) * S_LEN + si) = pack;
      }
    return;
  }
  // ---- q/k: RMSNorm + RoPE (+gain for q)
  float gain = 1.f;
  if (hc0 < 1024) gain = q_gain[hc0 >> 6] * 0.125f;  // fold softmax scale
#pragma unroll
  for (int mi = 0; mi < 2; mi++)
#pragma unroll
    for (int r = 0; r < 4; r++) {
      float ss = 0.f;
#pragma unroll
      for (int ni = 0; ni < 4; ni++) { float t = acc[mi][ni][r]; ss += t * t; }
#pragma unroll
      for (int off = 8; off >= 1; off >>= 1) ss += __shfl_xor(ss, off);
      float scl = rsqrtf(ss * (1.f / 64.f) + 1e-6f);
      int s = (m0 + wm + mi * 16 + quad * 4 + r) & (S_LEN - 1);
#pragma unroll
      for (int ni = 0; ni < 2; ni++) {
        float v1 = acc[mi][ni][r] * scl;
        float v2 = acc[mi][ni + 2][r] * scl;
        float fr = (float)(ni * 16 + fidx);
        float ang = (float)s * __expf(fr * -0.28782313662425575f);  // ln(1e4)/32
        float sn, cs;
        __sincosf(ang, &sn, &cs);
        acc[mi][ni][r]     = (v1 * cs + v2 * sn) * gain;
        acc[mi][ni + 2][r] = (-v1 * sn + v2 * cs) * gain;
      }
    }
#pragma unroll
  for (int mi = 0; mi < 2; mi++)
#pragma unroll
    for (int ni = 0; ni < 4; ni++)
#pragma unroll
      for (int r = 0; r < 4; r++) {
        int gr = m0 + wm + mi * 16 + quad * 4 + r;
        int gc = n0 + wn + ni * 16 + fidx;
        C[(size_t)gr * N + gc] = (bf16_t)acc[mi][ni][r];
      }
}

// ---------------- out-proj GEMM: 64x128 tile, BK=64, dbuf + counted vmcnt ---
// R6-verified; 512 blocks = 2.0/CU balanced. XCD swizzle: 512 = 8 x 64.
__global__ __launch_bounds__(256) void gemm_bt_f32(
    const bf16_t* __restrict__ A, const bf16_t* __restrict__ B,
    float* __restrict__ C, int N, int K) {
  __shared__ bf16_t As[2][64 * 64];
  __shared__ bf16_t Bs[2][128 * 64];
  const int tid = threadIdx.x;
  const int lane = tid & 63;
  const int w = tid >> 6;
  const int wm = (w & 1) << 5, wn = (w >> 1) << 6;
  const int orig = blockIdx.y * gridDim.x + blockIdx.x;   // 0..511
  const int id = (orig & 7) * 64 + (orig >> 3);           // bijective (512%8==0)
  const int m0 = (id >> 3) << 6, n0 = (id & 7) << 7;
  const int fidx = lane & 15, quad = lane >> 4;
  f32x4 acc[2][4] = {};
  int ra0 = (tid + 0) >> 3,   sa0 = ((tid + 0) & 7) ^ (ra0 & 7);
  int ra1 = (tid + 256) >> 3, sa1 = ((tid + 256) & 7) ^ (ra1 & 7);
  const bf16_t* Ag0 = A + (size_t)(m0 + ra0) * K + sa0 * 8;
  const bf16_t* Ag1 = A + (size_t)(m0 + ra1) * K + sa1 * 8;
  const bf16_t* Bg[4];
#pragma unroll
  for (int j = 0; j < 4; j++) {
    int c = tid + j * 256, r = c >> 3, s = (c & 7) ^ (r & 7);
    Bg[j] = B + (size_t)(n0 + r) * K + s * 8;
  }
  int aoff[2][2], boff[4][2];
#pragma unroll
  for (int mi = 0; mi < 2; mi++) {
    int row = wm + mi * 16 + fidx;
#pragma unroll
    for (int half = 0; half < 2; half++)
      aoff[mi][half] = row * 64 + (((half * 4 + quad) ^ (row & 7)) * 8);
  }
#pragma unroll
  for (int ni = 0; ni < 4; ni++) {
    int row = wn + ni * 16 + fidx;
#pragma unroll
    for (int half = 0; half < 2; half++)
      boff[ni][half] = row * 64 + (((half * 4 + quad) ^ (row & 7)) * 8);
  }
  async_load16(Ag0, &As[0][tid * 8]);
  async_load16(Ag1, &As[0][(tid + 256) * 8]);
#pragma unroll
  for (int j = 0; j < 4; j++)
    async_load16(Bg[j], &Bs[0][(tid + j * 256) * 8]);
  int cur = 0;
  for (int kt = 0; kt < K; kt += 64) {
    const int nk = kt + 64;
    if (nk < K) {
      async_load16(Ag0 + nk, &As[cur ^ 1][tid * 8]);
      async_load16(Ag1 + nk, &As[cur ^ 1][(tid + 256) * 8]);
#pragma unroll
      for (int j = 0; j < 4; j++)
        async_load16(Bg[j] + nk, &Bs[cur ^ 1][(tid + j * 256) * 8]);
      asm volatile("s_waitcnt vmcnt(6)" ::: "memory");
    } else {
      asm volatile("s_waitcnt vmcnt(0)" ::: "memory");
    }
    __builtin_amdgcn_s_barrier();
    __builtin_amdgcn_sched_barrier(0);
    bf16x8 af[2][2], bfr[4][2];
#pragma unroll
    for (int mi = 0; mi < 2; mi++)
#pragma unroll
      for (int half = 0; half < 2; half++)
        af[mi][half] = *(const bf16x8*)(&As[cur][aoff[mi][half]]);
#pragma unroll
    for (int ni = 0; ni < 4; ni++)
#pragma unroll
      for (int half = 0; half < 2; half++)
        bfr[ni][half] = *(const bf16x8*)(&Bs[cur][boff[ni][half]]);
#pragma unroll
    for (int half = 0; half < 2; half++)
#pragma unroll
      for (int mi = 0; mi < 2; mi++)
#pragma unroll
        for (int ni = 0; ni < 4; ni++)
          acc[mi][ni] = __builtin_amdgcn_mfma_f32_16x16x32_bf16(
              af[mi][half], bfr[ni][half], acc[mi][ni], 0, 0, 0);
    asm volatile("s_waitcnt lgkmcnt(0)" ::: "memory");
    __builtin_amdgcn_s_barrier();
    cur ^= 1;
  }
#pragma unroll
  for (int mi = 0; mi < 2; mi++)
#pragma unroll
    for (int ni = 0; ni < 4; ni++)
#pragma unroll
      for (int r = 0; r < 4; r++) {
        int gr = m0 + wm + mi * 16 + quad * 4 + r;
        int gc = n0 + wn + ni * 16 + fidx;
        C[(size_t)gr * N + gc] = acc[mi][ni][r];
      }
}

// ---------------- MFMA flash attention, k-split x2 (R9) ---------------------
// R6-verified body. NEW: 512 threads = 4 heads x 2 kv-range splits. With the
// FIXED-SHIFT softmax (exp(s-8), |s|<=8 exact), partial numerators/denominators
// over disjoint k-ranges ADD EXACTLY -> split s=1 publishes partial o/ps via
// LDS, one __syncthreads, s=0 adds and runs the unchanged epilogue.
// Waves/SIMD: 2 -> 4 (hides the serial QK->exp->shfl->PV chain).
// XCD swizzle: 512 blocks = 8 XCDs x 64 -> each XCD owns one (b,g) slab.
#define FIXMAX 8.0f
#define OST 72  // O stage row stride: 144 B = 9*16 B, aligned
__global__ __launch_bounds__(512) void attn_mfma(
    const bf16_t* __restrict__ qkv, const bf16_t* __restrict__ vt,
    bf16_t* __restrict__ yb) {
  __shared__ f32x4 po[4][2][4][64];   // 32 KB: upper-split partial O
  __shared__ float pps[4][2][64];     // 2 KB : upper-split partial rowsum
  __shared__ bf16_t ob[4][32 * OST];  // 18 KB: output staging (lower warps)
  const int tid = threadIdx.x, lane = tid & 63, w = tid >> 6;
  const int hw = w & 3, sp = w >> 2;          // head-in-group, split index
  const int col = lane & 15, quad = lane >> 4;
  const int orig = blockIdx.z * 256 + blockIdx.y * 64 + blockIdx.x;  // 0..511
  const int id = (orig & 7) * 64 + (orig >> 3);                      // bijective
  const int q0 = (id & 63) * 32, g = (id >> 6) & 3, b = id >> 8;
  const int h = g * 4 + hw;

  bf16x8 qf[2][2];
#pragma unroll
  for (int t = 0; t < 2; t++) {
    const bf16_t* qb =
        qkv + ((size_t)b * S_LEN + q0 + t * 16 + col) * QKV_COLS + h * 64 + quad * 8;
    qf[t][0] = *(const bf16x8*)qb;
    qf[t][1] = *(const bf16x8*)(qb + 32);
  }
  const bf16_t* kbase = qkv + (size_t)b * S_LEN * QKV_COLS + 1024 + g * 64 + quad * 8;
  const bf16_t* vbase = vt + ((size_t)((b * 4 + g) * 64) + col) * S_LEN + quad * 8;

  f32x4 o[2][4] = {};
  float ps[2] = {};   // per-lane partial row sum for q = col

  const int c_lo = max(0, (q0 - 255) >> 5);
  const int c_hi = (q0 + 31) >> 5;
  const int nc = c_hi - c_lo + 1;
  const int c_mid = c_lo + ((nc + 1) >> 1);
  const int my_lo = sp ? c_mid : c_lo;
  const int my_hi = sp ? c_hi : (c_mid - 1);

  for (int c = my_lo; c <= my_hi; c++) {
    const int k0 = c * 32;
    bf16x8 kf[2][2];
#pragma unroll
    for (int nt = 0; nt < 2; nt++) {
      const bf16_t* kp = kbase + (size_t)(k0 + nt * 16 + col) * QKV_COLS;
      kf[nt][0] = *(const bf16x8*)kp;
      kf[nt][1] = *(const bf16x8*)(kp + 32);
    }
    bf16x8 vf[4];
#pragma unroll
    for (int nt2 = 0; nt2 < 4; nt2++)
      vf[nt2] = *(const bf16x8*)(vbase + (size_t)(nt2 * 16) * S_LEN + k0);

#pragma unroll
    for (int t = 0; t < 2; t++) {
      const int qt0 = q0 + t * 16;
      if (k0 > qt0 + 15) continue;          // fully above diagonal for this tile
      // S^T[k][q]: rows k = k0 + nt*16 + quad*4 + r, cols q = qt0 + col
      f32x4 st[2];
#pragma unroll
      for (int nt = 0; nt < 2; nt++) {
        f32x4 a = {};
        a = __builtin_amdgcn_mfma_f32_16x16x32_bf16(kf[nt][0], qf[t][0], a, 0, 0, 0);
        a = __builtin_amdgcn_mfma_f32_16x16x32_bf16(kf[nt][1], qf[t][1], a, 0, 0, 0);
        st[nt] = a;
      }
      const bool needmask = (k0 + 31 > qt0) || (k0 < qt0 - 224);  // wave-uniform
      float p2[2][4];
      if (needmask) {
        int q = qt0 + col;
#pragma unroll
        for (int nt = 0; nt < 2; nt++)
#pragma unroll
          for (int r = 0; r < 4; r++) {
            int k = k0 + nt * 16 + quad * 4 + r;
            bool valid = (k <= q) && (q - k < 256);
            p2[nt][r] = valid ? __expf(st[nt][r] - FIXMAX) : 0.f;
          }
      } else {
#pragma unroll
        for (int nt = 0; nt < 2; nt++)
#pragma unroll
          for (int r = 0; r < 4; r++)
            p2[nt][r] = __expf(st[nt][r] - FIXMAX);
      }
#pragma unroll
      for (int nt = 0; nt < 2; nt++)
#pragma unroll
        for (int r = 0; r < 4; r++) ps[t] += p2[nt][r];
      // pack pairs and redistribute to A-fragment layout:
      // target (col,quad) dword m holds P[q=col][k = quad*8 + 2m, 2m+1]
      uint32_t pk0[2], pk1[2];
      pk0[0] = pkbf(p2[0][0], p2[0][1]); pk0[1] = pkbf(p2[0][2], p2[0][3]);
      pk1[0] = pkbf(p2[1][0], p2[1][1]); pk1[1] = pkbf(p2[1][2], p2[1][3]);
      uint32_t w32[4];
#pragma unroll
      for (int m = 0; m < 4; m++) {
        int srclane = col + 16 * ((2 * quad + (m >> 1)) & 3);
        uint32_t a0 = (uint32_t)__shfl((int)pk0[m & 1], srclane);
        uint32_t a1 = (uint32_t)__shfl((int)pk1[m & 1], srclane);
        w32[m] = (quad < 2) ? a0 : a1;
      }
      union { uint32_t u[4]; bf16x8 v; } pu;
      pu.u[0] = w32[0]; pu.u[1] = w32[1]; pu.u[2] = w32[2]; pu.u[3] = w32[3];
      bf16x8 pf = pu.v;
#pragma unroll
      for (int nt2 = 0; nt2 < 4; nt2++)
        o[t][nt2] = __builtin_amdgcn_mfma_f32_16x16x32_bf16(pf, vf[nt2], o[t][nt2], 0, 0, 0);
    }
  }
  // ---- upper split publishes exact partials (fixed shift -> additive)
  if (sp) {
#pragma unroll
    for (int t = 0; t < 2; t++) {
#pragma unroll
      for (int nt2 = 0; nt2 < 4; nt2++) po[hw][t][nt2][lane] = o[t][nt2];
      pps[hw][t][lane] = ps[t];
    }
  }
  __syncthreads();
  if (sp == 0) {
#pragma unroll
    for (int t = 0; t < 2; t++) {
#pragma unroll
      for (int nt2 = 0; nt2 < 4; nt2++) o[t][nt2] += po[hw][t][nt2][lane];
      ps[t] += pps[hw][t][lane];
    }
    // ---- row-sum reduce (across quads), per-output-row inverse, store
#pragma unroll
    for (int t = 0; t < 2; t++) {
      float v = ps[t];
      v += __shfl_xor(v, 16);
      v += __shfl_xor(v, 32);
      float il = 1.f / v;               // inverse row sum for q = col
      float il4[4];
#pragma unroll
      for (int r = 0; r < 4; r++) il4[r] = __shfl(il, quad * 4 + r);
      int row0 = t * 16 + quad * 4;
#pragma unroll
      for (int nt2 = 0; nt2 < 4; nt2++)
#pragma unroll
        for (int r = 0; r < 4; r++)
          ob[hw][(row0 + r) * OST + nt2 * 16 + col] = (bf16_t)(o[t][nt2][r] * il4[r]);
    }
    asm volatile("s_waitcnt lgkmcnt(0)" ::: "memory");
#pragma unroll
    for (int it = 0; it < 4; it++) {
      int row = it * 8 + (lane >> 3);       // 0..31
      int d0 = (lane & 7) * 8;
      bf16x8 v8 = *(const bf16x8*)(ob[hw] + row * OST + d0);
      *(bf16x8*)(yb + ((size_t)b * S_LEN + q0 + row) * 1024 + h * 64 + d0) = v8;
    }
  }
}

extern "C" void kernel_launch(void* const* d_in, const int* in_sizes, int n_in,
                              void* d_out, int out_size, void* d_ws, size_t ws_size,
                              hipStream_t stream) {
  const float* x        = (const float*)d_in[0];
  const float* Wq       = (const float*)d_in[1];
  const float* Wk       = (const float*)d_in[2];
  const float* Wv       = (const float*)d_in[3];
  const float* Wo       = (const float*)d_in[4];
  const float* q_gain   = (const float*)d_in[5];
  const float* pair_mix = (const float*)d_in[6];
  float* out = (float*)d_out;

  bf16_t* ws    = (bf16_t*)d_ws;
  bf16_t* xb    = ws;                   // 4096*1024
  bf16_t* wqkvb = xb + 4096 * 1024;     // 1536*1024
  bf16_t* wob   = wqkvb + 1536 * 1024;  // 1024*1024 (premixed)
  bf16_t* qkvb  = wob + 1024 * 1024;    // 4096*1536
  bf16_t* yb    = qkvb + 4096 * 1536;   // 4096*1024
  bf16_t* vt    = yb + 4096 * 1024;     // 8*64*2048 (total ~36.7 MB)

  convert_all<<<6656, 256, 0, stream>>>(
      (const float4*)x, (const float4*)Wq, (const float4*)Wk, (const float4*)Wv,
      (const float4*)Wo, pair_mix, (bf16x4*)xb, (bf16x4*)wqkvb, (bf16x4*)wob);
  gemm_qkv<<<dim3(12, 64), 256, 0, stream>>>(xb, wqkvb, qkvb, vt, q_gain, 1536, 1024);
  attn_mfma<<<dim3(64, 4, 2), 512, 0, stream>>>(qkvb, vt, yb);
  gemm_bt_f32<<<dim3(8, 64), 256, 0, stream>>>(yb, wob, out, 1024, 1024);
}